// Round 1
// baseline (51.510 us; speedup 1.0000x reference)
//
#include <hip/hip_runtime.h>
#include <stdint.h>

#define S_TOT 32768
#define MC_DIM 128
#define O_DIM 128
#define BN_EPS 1e-5f
#define S_TILE 128

typedef __attribute__((ext_vector_type(8))) short short8;
typedef __attribute__((ext_vector_type(4))) float f32x4;

static __device__ __forceinline__ unsigned short f2bf(float f) {
    union { float f; unsigned int u; } v; v.f = f;
    unsigned int r = v.u + 0x7FFFu + ((v.u >> 16) & 1u);
    return (unsigned short)(r >> 16);
}

// ws layout (float units):
// [0..255]     pooled[B=2][MC=128]
// [256..263]   route per b: {e0, e1, w0, w1} (e stored as float)
// [512..1023]  bias2[E=4][O=128]   (beta - rmean*inv)
// [1024.. ]    W2 bf16 [E][O][MC]  (65536 ushort = 32768 float slots)

// ---------------- kernel 1: global average pool ----------------
__global__ __launch_bounds__(512) void k_pool(
    const float* __restrict__ f0, const float* __restrict__ f1,
    const float* __restrict__ f2, const float* __restrict__ f3,
    float* __restrict__ ws) {
    int bid = blockIdx.x;          // 0..255 = b*128 + c
    int b = bid >> 7, c = bid & 127;
    const float* fp = (c < 32) ? f0 : (c < 64) ? f1 : (c < 96) ? f2 : f3;
    const float4* base = (const float4*)(fp + ((size_t)b * 32 + (c & 31)) * S_TOT);
    int t = threadIdx.x;
    float s = 0.f;
    #pragma unroll
    for (int j = 0; j < 16; ++j) {          // 512 thr * 16 * 4 = 32768
        float4 v = base[t + j * 512];
        s += (v.x + v.y) + (v.z + v.w);
    }
    __shared__ float red[512];
    red[t] = s;
    __syncthreads();
    for (int off = 256; off > 0; off >>= 1) {
        if (t < off) red[t] += red[t + off];
        __syncthreads();
    }
    if (t == 0) ws[b * MC_DIM + c] = red[0] * (1.0f / S_TOT);
}

// ---------------- kernel 2: router + BN fold + W->bf16 ----------------
__global__ __launch_bounds__(256) void k_route(
    const float* __restrict__ Wc, const float* __restrict__ gamma,
    const float* __restrict__ beta, const float* __restrict__ rmean,
    const float* __restrict__ rvar, const float* __restrict__ Wr,
    const float* __restrict__ br, float* __restrict__ ws,
    float* __restrict__ out_aux) {
    int t = threadIdx.x;
    __shared__ float logits[8];

    // phase A: logits[b][e], one 32-lane group per (b,e)
    {
        int g = t >> 5, li = t & 31;
        int b = g >> 2, e = g & 3;
        float p = 0.f;
        #pragma unroll
        for (int j = 0; j < 4; ++j) {
            int c = li + j * 32;
            p += ws[b * MC_DIM + c] * Wr[e * MC_DIM + c];
        }
        #pragma unroll
        for (int m = 16; m >= 1; m >>= 1) p += __shfl_xor(p, m, 32);
        if (li == 0) logits[g] = p + br[e];
    }
    __syncthreads();

    if (t == 0) {
        float probs[2][4];
        int top1[2];
        for (int b = 0; b < 2; ++b) {
            float mx = logits[b * 4];
            for (int e = 1; e < 4; ++e) mx = fmaxf(mx, logits[b * 4 + e]);
            float sum = 0.f;
            for (int e = 0; e < 4; ++e) { probs[b][e] = expf(logits[b * 4 + e] - mx); sum += probs[b][e]; }
            for (int e = 0; e < 4; ++e) probs[b][e] /= sum;
            int e0 = 0; float v0 = probs[b][0];
            for (int e = 1; e < 4; ++e) if (probs[b][e] > v0) { v0 = probs[b][e]; e0 = e; }
            int e1 = -1; float v1 = -1.f;
            for (int e = 0; e < 4; ++e) if (e != e0 && probs[b][e] > v1) { v1 = probs[b][e]; e1 = e; }
            float inv = 1.f / (v0 + v1);
            ws[256 + b * 4 + 0] = (float)e0;
            ws[256 + b * 4 + 1] = (float)e1;
            ws[256 + b * 4 + 2] = v0 * inv;
            ws[256 + b * 4 + 3] = v1 * inv;
            top1[b] = e0;
        }
        float aux = 0.f;
        for (int e = 0; e < 4; ++e) {
            float fe = 0.5f * ((top1[0] == e) + (top1[1] == e));
            float pe = 0.5f * (probs[0][e] + probs[1][e]);
            aux += fe * pe;
        }
        out_aux[0] = 4.f * aux;
    }

    // phase B1: bias2 = beta - rmean*inv
    for (int i = t; i < 512; i += 256) {
        float inv = gamma[i] * rsqrtf(rvar[i] + BN_EPS);
        ws[512 + i] = beta[i] - rmean[i] * inv;
    }
    // phase B2: W2 = bf16(Wc * inv)
    unsigned short* W2 = (unsigned short*)(ws + 1024);
    const float4* Wc4 = (const float4*)Wc;
    for (int i = t; i < 16384; i += 256) {   // quads: 65536/4
        int eo = i >> 5;                     // 32 quads per (e,o) row
        float inv = gamma[eo] * rsqrtf(rvar[eo] + BN_EPS);
        float4 w = Wc4[i];
        uint2 pk;
        pk.x = (unsigned int)f2bf(w.x * inv) | ((unsigned int)f2bf(w.y * inv) << 16);
        pk.y = (unsigned int)f2bf(w.z * inv) | ((unsigned int)f2bf(w.w * inv) << 16);
        ((uint2*)W2)[i] = pk;
    }
}

// ---------------- kernel 3: dual-expert GEMM + BN + ReLU + combine ----------------
__global__ __launch_bounds__(256, 2) void k_moe(
    const float* __restrict__ f0, const float* __restrict__ f1,
    const float* __restrict__ f2, const float* __restrict__ f3,
    const float* __restrict__ ws, float* __restrict__ out) {
    __shared__ uint4 lds_raw[2048];          // 32 KB: xT[s=128][c=128] bf16, granule-xor swizzled
    char* lds = (char*)lds_raw;

    int bid = blockIdx.x;                    // 512 blocks
    int b = bid >> 8;
    int st = bid & 255;
    int s0 = st * S_TILE;
    int t = threadIdx.x;

    // ---- stage x tile -> LDS (bf16, transposed, swizzled) ----
    // layout: byte(s, c) = s*256 + ((c>>3) ^ (s&15))*16 + (c&7)*2
    #pragma unroll
    for (int m = 0; m < 4; ++m) {
        const float* fp = (m == 0) ? f0 : (m == 1) ? f1 : (m == 2) ? f2 : f3;
        #pragma unroll
        for (int it = 0; it < 4; ++it) {
            int lin = it * 256 + t;          // 0..1023 = cql(8) x sl(128)
            int cql = lin >> 7;              // local c-quad 0..7
            int sl = lin & 127;
            const float* src = fp + ((size_t)b * 32 + cql * 4) * S_TOT + s0 + sl;
            float v0 = src[0];
            float v1 = src[S_TOT];
            float v2 = src[2 * (size_t)S_TOT];
            float v3 = src[3 * (size_t)S_TOT];
            int cq = m * 8 + cql;            // global c-quad 0..31
            int gr = cq >> 1, half = cq & 1;
            int gswz = gr ^ (sl & 15);
            int byte = sl * 256 + gswz * 16 + half * 8;
            uint2 pk;
            pk.x = (unsigned int)f2bf(v0) | ((unsigned int)f2bf(v1) << 16);
            pk.y = (unsigned int)f2bf(v2) | ((unsigned int)f2bf(v3) << 16);
            *(uint2*)(lds + byte) = pk;
        }
    }

    // route info (written by k_route)
    int e0 = (int)ws[256 + b * 4 + 0];
    int e1 = (int)ws[256 + b * 4 + 1];
    float w0 = ws[256 + b * 4 + 2];
    float w1 = ws[256 + b * 4 + 3];
    const unsigned short* W2 = (const unsigned short*)(ws + 1024);
    const float* bias2 = ws + 512;

    __syncthreads();

    int wv = t >> 6, l = t & 63;
    int o0 = wv * 32;                        // wave's o range: 32 rows
    int lr = l & 15, lg = l >> 4;

    f32x4 acc[2][2][8];
    #pragma unroll
    for (int ee = 0; ee < 2; ++ee)
        #pragma unroll
        for (int of = 0; of < 2; ++of)
            #pragma unroll
            for (int sf = 0; sf < 8; ++sf)
                acc[ee][of][sf] = (f32x4){0.f, 0.f, 0.f, 0.f};

    #pragma unroll
    for (int kk = 0; kk < 4; ++kk) {
        short8 a[2][2];
        #pragma unroll
        for (int ee = 0; ee < 2; ++ee) {
            int e = ee ? e1 : e0;
            #pragma unroll
            for (int of = 0; of < 2; ++of) {
                int o = o0 + of * 16 + lr;   // A: row = lane&15
                a[ee][of] = *(const short8*)(W2 + ((size_t)(e * O_DIM + o) * MC_DIM + kk * 32 + lg * 8));
            }
        }
        #pragma unroll
        for (int sf = 0; sf < 8; ++sf) {
            int sl = sf * 16 + lr;           // B: col = lane&15
            int gr = kk * 4 + lg;            // granule holds k = 8*gr .. 8*gr+7
            int byte = sl * 256 + (gr ^ lr) * 16;   // sl&15 == lr
            short8 bb = *(const short8*)(lds + byte);
            #pragma unroll
            for (int ee = 0; ee < 2; ++ee)
                #pragma unroll
                for (int of = 0; of < 2; ++of)
                    acc[ee][of][sf] = __builtin_amdgcn_mfma_f32_16x16x32_bf16(
                        a[ee][of], bb, acc[ee][of][sf], 0, 0, 0);
        }
    }

    // ---- epilogue: bias + relu + weighted combine, fp32 out ----
    #pragma unroll
    for (int of = 0; of < 2; ++of) {
        #pragma unroll
        for (int r = 0; r < 4; ++r) {
            int o = o0 + of * 16 + lg * 4 + r;   // C/D: row = (lane>>4)*4 + reg
            float bA = bias2[e0 * O_DIM + o];
            float bB = bias2[e1 * O_DIM + o];
            float* orow = out + ((size_t)(b * O_DIM + o)) * S_TOT + s0;
            #pragma unroll
            for (int sf = 0; sf < 8; ++sf) {
                float y0 = fmaxf(acc[0][of][sf][r] + bA, 0.f);
                float y1 = fmaxf(acc[1][of][sf][r] + bB, 0.f);
                orow[sf * 16 + lr] = w0 * y0 + w1 * y1;
            }
        }
    }
}

extern "C" void kernel_launch(void* const* d_in, const int* in_sizes, int n_in,
                              void* d_out, int out_size, void* d_ws, size_t ws_size,
                              hipStream_t stream) {
    const float* f0    = (const float*)d_in[0];
    const float* f1    = (const float*)d_in[1];
    const float* f2    = (const float*)d_in[2];
    const float* f3    = (const float*)d_in[3];
    const float* Wc    = (const float*)d_in[4];
    const float* gamma = (const float*)d_in[5];
    const float* beta  = (const float*)d_in[6];
    const float* rmean = (const float*)d_in[7];
    const float* rvar  = (const float*)d_in[8];
    const float* Wr    = (const float*)d_in[9];
    const float* br    = (const float*)d_in[10];
    float* ws  = (float*)d_ws;
    float* out = (float*)d_out;

    hipLaunchKernelGGL(k_pool, dim3(256), dim3(512), 0, stream, f0, f1, f2, f3, ws);
    hipLaunchKernelGGL(k_route, dim3(1), dim3(256), 0, stream,
                       Wc, gamma, beta, rmean, rvar, Wr, br, ws, out + (size_t)8388608);
    hipLaunchKernelGGL(k_moe, dim3(512), dim3(256), 0, stream, f0, f1, f2, f3, ws, out);
}

// Round 3
// 48.627 us; speedup vs baseline: 1.0593x; 1.0593x over previous
//
#include <hip/hip_runtime.h>
#include <stdint.h>

#define S_TOT 32768
#define MC_DIM 128
#define O_DIM 128
#define BN_EPS 1e-5f
#define S_TILE 128

// ws layout (float units):
#define WS_POOL  0      // [0..255]    pooled channel SUMS [B=2][MC=128] (memset 0 each call)
#define WS_ROUTE 256    // [256..263]  per b: {e0, e1, w0, w1}
#define WS_BIAS  512    // [512..1023] bias2[E=4][O=128]
#define WS_W2    1024   // [1024..33791] W2 bf16 [E][O][MC] (65536 ushort)
#define WS_XT    33792  // 512 tiles * 8192 floats (32KB/tile) = 16MB, bf16 swizzled xT

typedef __attribute__((ext_vector_type(8))) short short8;
typedef __attribute__((ext_vector_type(4))) float f32x4;

static __device__ __forceinline__ unsigned short f2bf(float f) {
    union { float f; unsigned int u; } v; v.f = f;
    unsigned int r = v.u + 0x7FFFu + ((v.u >> 16) & 1u);
    return (unsigned short)(r >> 16);
}

// ---------------- K1: x -> bf16 swizzled xT tiles + pool partials + W2 fold ----------------
__global__ __launch_bounds__(256, 2) void k_prep(
    const float* __restrict__ f0, const float* __restrict__ f1,
    const float* __restrict__ f2, const float* __restrict__ f3,
    const float* __restrict__ Wc, const float* __restrict__ gamma,
    const float* __restrict__ beta, const float* __restrict__ rmean,
    const float* __restrict__ rvar, float* __restrict__ ws) {

    __shared__ float lds_pool[2][128];

    int bid = blockIdx.x;                    // 512 blocks = b(2) x st(256)
    int b = bid >> 8;
    int st = bid & 255;
    int s0 = st * S_TILE;
    int t = threadIdx.x;
    int wv = t >> 6, l = t & 63;

    // distributed W2 = bf16(Wc * inv) and bias2 = beta - rmean*inv
    if (t < 32) {
        int i = bid * 32 + t;                // 16384 float4 quads total
        int eo = i >> 5;
        float inv = gamma[eo] * rsqrtf(rvar[eo] + BN_EPS);
        float4 w = ((const float4*)Wc)[i];
        uint2 pk;
        pk.x = (unsigned int)f2bf(w.x * inv) | ((unsigned int)f2bf(w.y * inv) << 16);
        pk.y = (unsigned int)f2bf(w.z * inv) | ((unsigned int)f2bf(w.w * inv) << 16);
        ((uint2*)(ws + WS_W2))[i] = pk;
    } else if (t == 32) {
        float inv = gamma[bid] * rsqrtf(rvar[bid] + BN_EPS);
        ws[WS_BIAS + bid] = beta[bid] - rmean[bid] * inv;
    }

    char* xt = (char*)(ws + WS_XT) + (size_t)bid * 32768;

    // stage x tile -> ws (bf16, transposed, swizzled) + pool partials
    // layout within tile: byte(s, c) = s*256 + ((c>>3) ^ (s&15))*16 + (c&7)*2
    #pragma unroll
    for (int m = 0; m < 4; ++m) {
        const float* fp = (m == 0) ? f0 : (m == 1) ? f1 : (m == 2) ? f2 : f3;
        #pragma unroll
        for (int it = 0; it < 4; ++it) {
            int lin = it * 256 + t;          // cql(8) x sl(128)
            int cql = lin >> 7;              // constant within a wave
            int sl = lin & 127;
            const float* src = fp + ((size_t)b * 32 + cql * 4) * S_TOT + s0 + sl;
            float v0 = src[0];
            float v1 = src[S_TOT];
            float v2 = src[2 * (size_t)S_TOT];
            float v3 = src[3 * (size_t)S_TOT];
            int cq = m * 8 + cql;            // global c-quad 0..31
            int gr = cq >> 1, half = cq & 1;
            int gswz = gr ^ (sl & 15);
            int byte = sl * 256 + gswz * 16 + half * 8;
            uint2 pk;
            pk.x = (unsigned int)f2bf(v0) | ((unsigned int)f2bf(v1) << 16);
            pk.y = (unsigned int)f2bf(v2) | ((unsigned int)f2bf(v3) << 16);
            *(uint2*)(xt + byte) = pk;
            // pool partials: this wave's 64 lanes hold 64 distinct s for these 4 channels
            float p0 = v0, p1 = v1, p2 = v2, p3 = v3;
            #pragma unroll
            for (int msk = 32; msk >= 1; msk >>= 1) {
                p0 += __shfl_xor(p0, msk);
                p1 += __shfl_xor(p1, msk);
                p2 += __shfl_xor(p2, msk);
                p3 += __shfl_xor(p3, msk);
            }
            if (l == 0) {
                int c = m * 32 + cql * 4;
                lds_pool[wv & 1][c + 0] = p0;
                lds_pool[wv & 1][c + 1] = p1;
                lds_pool[wv & 1][c + 2] = p2;
                lds_pool[wv & 1][c + 3] = p3;
            }
        }
    }
    __syncthreads();
    if (t < 128) {
        float v = lds_pool[0][t] + lds_pool[1][t];
        atomicAdd(&ws[WS_POOL + b * MC_DIM + t], v);
    }
}

// ---------------- K2: router + top-2 + aux ----------------
__global__ __launch_bounds__(64) void k_route(
    const float* __restrict__ Wr, const float* __restrict__ br,
    float* __restrict__ ws, float* __restrict__ out_aux) {
    int l = threadIdx.x;
    const float s_inv = 1.0f / (float)S_TOT;
    float x0 = ws[WS_POOL + l] * s_inv;
    float x1 = ws[WS_POOL + 64 + l] * s_inv;
    float y0 = ws[WS_POOL + 128 + l] * s_inv;
    float y1 = ws[WS_POOL + 192 + l] * s_inv;
    float lg[8];
    #pragma unroll
    for (int e = 0; e < 4; ++e) {
        float wc0 = Wr[e * MC_DIM + l];
        float wc1 = Wr[e * MC_DIM + 64 + l];
        lg[e] = x0 * wc0 + x1 * wc1;
        lg[4 + e] = y0 * wc0 + y1 * wc1;
    }
    #pragma unroll
    for (int msk = 32; msk >= 1; msk >>= 1) {
        #pragma unroll
        for (int e = 0; e < 8; ++e) lg[e] += __shfl_xor(lg[e], msk);
    }
    if (l == 0) {
        float probs[2][4];
        int top1[2];
        #pragma unroll
        for (int bb = 0; bb < 2; ++bb) {
            float lo[4];
            for (int e = 0; e < 4; ++e) lo[e] = lg[bb * 4 + e] + br[e];
            float mx = fmaxf(fmaxf(lo[0], lo[1]), fmaxf(lo[2], lo[3]));
            float sum = 0.f;
            for (int e = 0; e < 4; ++e) { probs[bb][e] = expf(lo[e] - mx); sum += probs[bb][e]; }
            for (int e = 0; e < 4; ++e) probs[bb][e] /= sum;
            int e0 = 0; float v0 = probs[bb][0];
            for (int e = 1; e < 4; ++e) if (probs[bb][e] > v0) { v0 = probs[bb][e]; e0 = e; }
            int e1 = -1; float v1 = -1.f;
            for (int e = 0; e < 4; ++e) if (e != e0 && probs[bb][e] > v1) { v1 = probs[bb][e]; e1 = e; }
            float inv = 1.f / (v0 + v1);
            ws[WS_ROUTE + bb * 4 + 0] = (float)e0;
            ws[WS_ROUTE + bb * 4 + 1] = (float)e1;
            ws[WS_ROUTE + bb * 4 + 2] = v0 * inv;
            ws[WS_ROUTE + bb * 4 + 3] = v1 * inv;
            top1[bb] = e0;
        }
        float aux = 0.f;
        for (int e = 0; e < 4; ++e) {
            float fe = 0.5f * ((top1[0] == e) + (top1[1] == e));
            float pe = 0.5f * (probs[0][e] + probs[1][e]);
            aux += fe * pe;
        }
        out_aux[0] = 4.f * aux;
    }
}

// ---------------- K3: dual-expert GEMM + BN + ReLU + combine ----------------
__global__ __launch_bounds__(256, 2) void k_moe(
    const float* __restrict__ ws, float* __restrict__ out) {
    __shared__ uint4 lds_raw[2048];          // 32 KB: swizzled xT tile (as written by k_prep)
    char* lds = (char*)lds_raw;

    int bid = blockIdx.x;                    // 512 blocks
    int b = bid >> 8;
    int st = bid & 255;
    int s0 = st * S_TILE;
    int t = threadIdx.x;

    // stage tile: linear copy (swizzle pre-baked), fully coalesced, L3-hot
    const uint4* xsrc = (const uint4*)(ws + WS_XT) + (size_t)bid * 2048;
    #pragma unroll
    for (int j = 0; j < 8; ++j)
        lds_raw[j * 256 + t] = xsrc[j * 256 + t];

    int e0 = (int)ws[WS_ROUTE + b * 4 + 0];
    int e1 = (int)ws[WS_ROUTE + b * 4 + 1];
    float w0 = ws[WS_ROUTE + b * 4 + 2];
    float w1 = ws[WS_ROUTE + b * 4 + 3];
    const unsigned short* W2 = (const unsigned short*)(ws + WS_W2);
    const float* bias2 = ws + WS_BIAS;

    __syncthreads();

    int wv = t >> 6, l = t & 63;
    int o0 = wv * 32;
    int lr = l & 15, lg2 = l >> 4;

    f32x4 acc[2][2][8];
    #pragma unroll
    for (int ee = 0; ee < 2; ++ee)
        #pragma unroll
        for (int of = 0; of < 2; ++of)
            #pragma unroll
            for (int sf = 0; sf < 8; ++sf)
                acc[ee][of][sf] = (f32x4){0.f, 0.f, 0.f, 0.f};

    #pragma unroll
    for (int kk = 0; kk < 4; ++kk) {
        short8 a[2][2];
        #pragma unroll
        for (int ee = 0; ee < 2; ++ee) {
            int e = ee ? e1 : e0;
            #pragma unroll
            for (int of = 0; of < 2; ++of) {
                int o = o0 + of * 16 + lr;   // A: row = lane&15
                a[ee][of] = *(const short8*)(W2 + ((size_t)(e * O_DIM + o) * MC_DIM + kk * 32 + lg2 * 8));
            }
        }
        #pragma unroll
        for (int sf = 0; sf < 8; ++sf) {
            int sl = sf * 16 + lr;           // B: col = lane&15
            int gr = kk * 4 + lg2;
            int byte = sl * 256 + (gr ^ lr) * 16;
            short8 bb = *(const short8*)(lds + byte);
            #pragma unroll
            for (int ee = 0; ee < 2; ++ee)
                #pragma unroll
                for (int of = 0; of < 2; ++of)
                    acc[ee][of][sf] = __builtin_amdgcn_mfma_f32_16x16x32_bf16(
                        a[ee][of], bb, acc[ee][of][sf], 0, 0, 0);
        }
    }

    #pragma unroll
    for (int of = 0; of < 2; ++of) {
        #pragma unroll
        for (int r = 0; r < 4; ++r) {
            int o = o0 + of * 16 + lg2 * 4 + r;   // C/D: row = (lane>>4)*4 + reg
            float bA = bias2[e0 * O_DIM + o];
            float bB = bias2[e1 * O_DIM + o];
            float* orow = out + ((size_t)(b * O_DIM + o)) * S_TOT + s0;
            #pragma unroll
            for (int sf = 0; sf < 8; ++sf) {
                float y0 = fmaxf(acc[0][of][sf][r] + bA, 0.f);
                float y1 = fmaxf(acc[1][of][sf][r] + bB, 0.f);
                orow[sf * 16 + lr] = w0 * y0 + w1 * y1;
            }
        }
    }
}

extern "C" void kernel_launch(void* const* d_in, const int* in_sizes, int n_in,
                              void* d_out, int out_size, void* d_ws, size_t ws_size,
                              hipStream_t stream) {
    const float* f0    = (const float*)d_in[0];
    const float* f1    = (const float*)d_in[1];
    const float* f2    = (const float*)d_in[2];
    const float* f3    = (const float*)d_in[3];
    const float* Wc    = (const float*)d_in[4];
    const float* gamma = (const float*)d_in[5];
    const float* beta  = (const float*)d_in[6];
    const float* rmean = (const float*)d_in[7];
    const float* rvar  = (const float*)d_in[8];
    const float* Wr    = (const float*)d_in[9];
    const float* br    = (const float*)d_in[10];
    float* ws  = (float*)d_ws;
    float* out = (float*)d_out;

    hipMemsetAsync(d_ws, 0, 256 * sizeof(float), stream);
    hipLaunchKernelGGL(k_prep, dim3(512), dim3(256), 0, stream,
                       f0, f1, f2, f3, Wc, gamma, beta, rmean, rvar, ws);
    hipLaunchKernelGGL(k_route, dim3(1), dim3(64), 0, stream,
                       Wr, br, ws, out + (size_t)8388608);
    hipLaunchKernelGGL(k_moe, dim3(512), dim3(256), 0, stream, ws, out);
}

// Round 4
// 41.387 us; speedup vs baseline: 1.2446x; 1.1749x over previous
//
#include <hip/hip_runtime.h>
#include <stdint.h>

#define S_TOT 32768
#define MC_DIM 128
#define O_DIM 128
#define BN_EPS 1e-5f
#define S_TILE 128

// ws layout (float units):
#define WS_PART  0        // [512][128] per-block pool partial sums (every slot written each call)
#define WS_ROUTE 65536    // [8]   per b: {e0, e1, w0, w1}
#define WS_BIAS  65600    // [512] bias2[E=4][O=128]
#define WS_W2    66176    // 32768 float slots = W2 bf16 [E][O][MC] (65536 ushort)
#define WS_XT    98944    // 512 tiles * 8192 floats (32KB/tile) = 16MB, bf16 swizzled xT

typedef __attribute__((ext_vector_type(8))) short short8;
typedef __attribute__((ext_vector_type(4))) float f32x4;

static __device__ __forceinline__ unsigned short f2bf(float f) {
    union { float f; unsigned int u; } v; v.f = f;
    unsigned int r = v.u + 0x7FFFu + ((v.u >> 16) & 1u);
    return (unsigned short)(r >> 16);
}

// ---------------- K1: x -> bf16 swizzled xT tiles (via LDS, coalesced out) + pool partials + W2 fold ----------------
__global__ __launch_bounds__(256, 2) void k_prep(
    const float* __restrict__ f0, const float* __restrict__ f1,
    const float* __restrict__ f2, const float* __restrict__ f3,
    const float* __restrict__ Wc, const float* __restrict__ gamma,
    const float* __restrict__ beta, const float* __restrict__ rmean,
    const float* __restrict__ rvar, float* __restrict__ ws) {

    __shared__ uint4 tile[2048];             // 32 KB swizzled xT tile image
    __shared__ float lds_pool[2][128];
    char* lds = (char*)tile;

    int bid = blockIdx.x;                    // 512 blocks = b(2) x st(256)
    int b = bid >> 8;
    int st = bid & 255;
    int s0 = st * S_TILE;
    int t = threadIdx.x;
    int wv = t >> 6, l = t & 63;

    // distributed W2 = bf16(Wc * inv) and bias2 = beta - rmean*inv
    if (t < 32) {
        int i = bid * 32 + t;                // 16384 float4 quads total
        int eo = i >> 5;
        float inv = gamma[eo] * rsqrtf(rvar[eo] + BN_EPS);
        float4 w = ((const float4*)Wc)[i];
        uint2 pk;
        pk.x = (unsigned int)f2bf(w.x * inv) | ((unsigned int)f2bf(w.y * inv) << 16);
        pk.y = (unsigned int)f2bf(w.z * inv) | ((unsigned int)f2bf(w.w * inv) << 16);
        ((uint2*)(ws + WS_W2))[i] = pk;
    } else if (t == 32) {
        float inv = gamma[bid] * rsqrtf(rvar[bid] + BN_EPS);
        ws[WS_BIAS + bid] = beta[bid] - rmean[bid] * inv;
    }

    // stage x tile -> LDS (bf16, transposed, swizzled) + pool partials
    // layout within tile: byte(s, c) = s*256 + ((c>>3) ^ (s&15))*16 + (c&7)*2
    #pragma unroll
    for (int m = 0; m < 4; ++m) {
        const float* fp = (m == 0) ? f0 : (m == 1) ? f1 : (m == 2) ? f2 : f3;
        #pragma unroll
        for (int it = 0; it < 4; ++it) {
            int lin = it * 256 + t;          // cql(8) x sl(128)
            int cql = lin >> 7;              // constant within a wave
            int sl = lin & 127;
            const float* src = fp + ((size_t)b * 32 + cql * 4) * S_TOT + s0 + sl;
            float v0 = src[0];
            float v1 = src[S_TOT];
            float v2 = src[2 * (size_t)S_TOT];
            float v3 = src[3 * (size_t)S_TOT];
            int cq = m * 8 + cql;            // global c-quad 0..31
            int gr = cq >> 1, half = cq & 1;
            int gswz = gr ^ (sl & 15);
            int byte = sl * 256 + gswz * 16 + half * 8;
            uint2 pk;
            pk.x = (unsigned int)f2bf(v0) | ((unsigned int)f2bf(v1) << 16);
            pk.y = (unsigned int)f2bf(v2) | ((unsigned int)f2bf(v3) << 16);
            *(uint2*)(lds + byte) = pk;
            // pool partials: this wave's 64 lanes hold 64 distinct s for these 4 channels
            float p0 = v0, p1 = v1, p2 = v2, p3 = v3;
            #pragma unroll
            for (int msk = 32; msk >= 1; msk >>= 1) {
                p0 += __shfl_xor(p0, msk);
                p1 += __shfl_xor(p1, msk);
                p2 += __shfl_xor(p2, msk);
                p3 += __shfl_xor(p3, msk);
            }
            if (l == 0) {                    // (s-half = wv&1, channel) written exactly once
                int c = m * 32 + cql * 4;
                lds_pool[wv & 1][c + 0] = p0;
                lds_pool[wv & 1][c + 1] = p1;
                lds_pool[wv & 1][c + 2] = p2;
                lds_pool[wv & 1][c + 3] = p3;
            }
        }
    }
    __syncthreads();

    // coalesced tile write-out (swizzle pre-baked in LDS image)
    uint4* xt4 = (uint4*)(ws + WS_XT) + (size_t)bid * 2048;
    #pragma unroll
    for (int j = 0; j < 8; ++j)
        xt4[j * 256 + t] = tile[j * 256 + t];

    // per-block pool partial (no atomics)
    if (t < 128)
        ws[WS_PART + bid * 128 + t] = lds_pool[0][t] + lds_pool[1][t];
}

// ---------------- K2: partial reduce + router + top-2 + aux ----------------
__global__ __launch_bounds__(512) void k_route(
    const float* __restrict__ Wr, const float* __restrict__ br,
    float* __restrict__ ws, float* __restrict__ out_aux) {
    __shared__ float red[512];
    __shared__ float pooled[256];
    int t = threadIdx.x;

    // reduce 512 partials: pair p=(b,c) gets 2 threads (h = st-half)
    {
        int p = t & 255, h = t >> 8;
        int b = p >> 7, c = p & 127;
        float s = 0.f;
        const float* base = ws + WS_PART + ((size_t)(b * 256 + h * 128)) * 128 + c;
        #pragma unroll 8
        for (int j = 0; j < 128; ++j) s += base[j * 128];
        red[t] = s;
    }
    __syncthreads();
    if (t < 256) pooled[t] = red[t] + red[t + 256];
    __syncthreads();

    if (t < 64) {
        int l = t;
        const float s_inv = 1.0f / (float)S_TOT;
        float x0 = pooled[l] * s_inv;
        float x1 = pooled[64 + l] * s_inv;
        float y0 = pooled[128 + l] * s_inv;
        float y1 = pooled[192 + l] * s_inv;
        float lg[8];
        #pragma unroll
        for (int e = 0; e < 4; ++e) {
            float wc0 = Wr[e * MC_DIM + l];
            float wc1 = Wr[e * MC_DIM + 64 + l];
            lg[e] = x0 * wc0 + x1 * wc1;
            lg[4 + e] = y0 * wc0 + y1 * wc1;
        }
        #pragma unroll
        for (int msk = 32; msk >= 1; msk >>= 1) {
            #pragma unroll
            for (int e = 0; e < 8; ++e) lg[e] += __shfl_xor(lg[e], msk);
        }
        if (l == 0) {
            float probs[2][4];
            int top1[2];
            #pragma unroll
            for (int bb = 0; bb < 2; ++bb) {
                float lo[4];
                for (int e = 0; e < 4; ++e) lo[e] = lg[bb * 4 + e] + br[e];
                float mx = fmaxf(fmaxf(lo[0], lo[1]), fmaxf(lo[2], lo[3]));
                float sum = 0.f;
                for (int e = 0; e < 4; ++e) { probs[bb][e] = expf(lo[e] - mx); sum += probs[bb][e]; }
                for (int e = 0; e < 4; ++e) probs[bb][e] /= sum;
                int e0 = 0; float v0 = probs[bb][0];
                for (int e = 1; e < 4; ++e) if (probs[bb][e] > v0) { v0 = probs[bb][e]; e0 = e; }
                int e1 = -1; float v1 = -1.f;
                for (int e = 0; e < 4; ++e) if (e != e0 && probs[bb][e] > v1) { v1 = probs[bb][e]; e1 = e; }
                float inv = 1.f / (v0 + v1);
                ws[WS_ROUTE + bb * 4 + 0] = (float)e0;
                ws[WS_ROUTE + bb * 4 + 1] = (float)e1;
                ws[WS_ROUTE + bb * 4 + 2] = v0 * inv;
                ws[WS_ROUTE + bb * 4 + 3] = v1 * inv;
                top1[bb] = e0;
            }
            float aux = 0.f;
            for (int e = 0; e < 4; ++e) {
                float fe = 0.5f * ((top1[0] == e) + (top1[1] == e));
                float pe = 0.5f * (probs[0][e] + probs[1][e]);
                aux += fe * pe;
            }
            out_aux[0] = 4.f * aux;
        }
    }
}

// ---------------- K3: dual-expert GEMM + BN + ReLU + combine ----------------
__global__ __launch_bounds__(256, 2) void k_moe(
    const float* __restrict__ ws, float* __restrict__ out) {
    __shared__ uint4 lds_raw[2048];          // 32 KB: swizzled xT tile (as written by k_prep)
    char* lds = (char*)lds_raw;

    int bid = blockIdx.x;                    // 512 blocks
    int b = bid >> 8;
    int st = bid & 255;
    int s0 = st * S_TILE;
    int t = threadIdx.x;

    // stage tile: linear copy (swizzle pre-baked), fully coalesced, L3-hot
    const uint4* xsrc = (const uint4*)(ws + WS_XT) + (size_t)bid * 2048;
    #pragma unroll
    for (int j = 0; j < 8; ++j)
        lds_raw[j * 256 + t] = xsrc[j * 256 + t];

    int e0 = (int)ws[WS_ROUTE + b * 4 + 0];
    int e1 = (int)ws[WS_ROUTE + b * 4 + 1];
    float w0 = ws[WS_ROUTE + b * 4 + 2];
    float w1 = ws[WS_ROUTE + b * 4 + 3];
    const unsigned short* W2 = (const unsigned short*)(ws + WS_W2);
    const float* bias2 = ws + WS_BIAS;

    __syncthreads();

    int wv = t >> 6, l = t & 63;
    int o0 = wv * 32;
    int lr = l & 15, lg2 = l >> 4;

    f32x4 acc[2][2][8];
    #pragma unroll
    for (int ee = 0; ee < 2; ++ee)
        #pragma unroll
        for (int of = 0; of < 2; ++of)
            #pragma unroll
            for (int sf = 0; sf < 8; ++sf)
                acc[ee][of][sf] = (f32x4){0.f, 0.f, 0.f, 0.f};

    #pragma unroll
    for (int kk = 0; kk < 4; ++kk) {
        short8 a[2][2];
        #pragma unroll
        for (int ee = 0; ee < 2; ++ee) {
            int e = ee ? e1 : e0;
            #pragma unroll
            for (int of = 0; of < 2; ++of) {
                int o = o0 + of * 16 + lr;   // A: row = lane&15
                a[ee][of] = *(const short8*)(W2 + ((size_t)(e * O_DIM + o) * MC_DIM + kk * 32 + lg2 * 8));
            }
        }
        #pragma unroll
        for (int sf = 0; sf < 8; ++sf) {
            int sl = sf * 16 + lr;           // B: col = lane&15
            int gr = kk * 4 + lg2;
            int byte = sl * 256 + (gr ^ lr) * 16;
            short8 bb = *(const short8*)(lds + byte);
            #pragma unroll
            for (int ee = 0; ee < 2; ++ee)
                #pragma unroll
                for (int of = 0; of < 2; ++of)
                    acc[ee][of][sf] = __builtin_amdgcn_mfma_f32_16x16x32_bf16(
                        a[ee][of], bb, acc[ee][of][sf], 0, 0, 0);
        }
    }

    #pragma unroll
    for (int of = 0; of < 2; ++of) {
        #pragma unroll
        for (int r = 0; r < 4; ++r) {
            int o = o0 + of * 16 + lg2 * 4 + r;   // C/D: row = (lane>>4)*4 + reg
            float bA = bias2[e0 * O_DIM + o];
            float bB = bias2[e1 * O_DIM + o];
            float* orow = out + ((size_t)(b * O_DIM + o)) * S_TOT + s0;
            #pragma unroll
            for (int sf = 0; sf < 8; ++sf) {
                float y0 = fmaxf(acc[0][of][sf][r] + bA, 0.f);
                float y1 = fmaxf(acc[1][of][sf][r] + bB, 0.f);
                orow[sf * 16 + lr] = w0 * y0 + w1 * y1;
            }
        }
    }
}

extern "C" void kernel_launch(void* const* d_in, const int* in_sizes, int n_in,
                              void* d_out, int out_size, void* d_ws, size_t ws_size,
                              hipStream_t stream) {
    const float* f0    = (const float*)d_in[0];
    const float* f1    = (const float*)d_in[1];
    const float* f2    = (const float*)d_in[2];
    const float* f3    = (const float*)d_in[3];
    const float* Wc    = (const float*)d_in[4];
    const float* gamma = (const float*)d_in[5];
    const float* beta  = (const float*)d_in[6];
    const float* rmean = (const float*)d_in[7];
    const float* rvar  = (const float*)d_in[8];
    const float* Wr    = (const float*)d_in[9];
    const float* br    = (const float*)d_in[10];
    float* ws  = (float*)d_ws;
    float* out = (float*)d_out;

    hipLaunchKernelGGL(k_prep, dim3(512), dim3(256), 0, stream,
                       f0, f1, f2, f3, Wc, gamma, beta, rmean, rvar, ws);
    hipLaunchKernelGGL(k_route, dim3(1), dim3(512), 0, stream,
                       Wr, br, ws, out + (size_t)8388608);
    hipLaunchKernelGGL(k_moe, dim3(512), dim3(256), 0, stream, ws, out);
}

// Round 5
// 32.317 us; speedup vs baseline: 1.5939x; 1.2807x over previous
//
#include <hip/hip_runtime.h>
#include <stdint.h>

#define S_TOT 32768
#define MC_DIM 128
#define O_DIM 128
#define BN_EPS 1e-5f
#define S_TILE 128

// ws layout (float units):
#define WS_PART  0        // [512] per-block pool partials: idx = half*256 + (b*128+c)
#define WS_BIAS  512      // [512] bias2[E=4][O=128]
#define WS_W2    1024     // 32768 float slots = W2 bf16 [E][O][MC] (65536 ushort)

typedef __attribute__((ext_vector_type(8))) short short8;
typedef __attribute__((ext_vector_type(4))) float f32x4;

static __device__ __forceinline__ unsigned short f2bf(float f) {
    union { float f; unsigned int u; } v; v.f = f;
    unsigned int r = v.u + 0x7FFFu + ((v.u >> 16) & 1u);
    return (unsigned short)(r >> 16);
}

// ---------------- K1: pool partials + W2 fold ----------------
__global__ __launch_bounds__(256) void k_pool(
    const float* __restrict__ f0, const float* __restrict__ f1,
    const float* __restrict__ f2, const float* __restrict__ f3,
    const float* __restrict__ Wc, const float* __restrict__ gamma,
    const float* __restrict__ beta, const float* __restrict__ rmean,
    const float* __restrict__ rvar, float* __restrict__ ws) {

    __shared__ float red[256];
    int bid = blockIdx.x;                    // 512 = half(2) x b(2) x c(128)
    int half = bid >> 8, ch = bid & 255;
    int b = ch >> 7, c = ch & 127;
    int t = threadIdx.x;

    // distributed W2 = bf16(Wc * inv) and bias2 = beta - rmean*inv (verified r3/r4)
    if (t < 32) {
        int i = bid * 32 + t;                // 16384 float4 quads total
        int eo = i >> 5;
        float inv = gamma[eo] * rsqrtf(rvar[eo] + BN_EPS);
        float4 w = ((const float4*)Wc)[i];
        uint2 pk;
        pk.x = (unsigned int)f2bf(w.x * inv) | ((unsigned int)f2bf(w.y * inv) << 16);
        pk.y = (unsigned int)f2bf(w.z * inv) | ((unsigned int)f2bf(w.w * inv) << 16);
        ((uint2*)(ws + WS_W2))[i] = pk;
    } else if (t == 32) {
        float inv = gamma[bid] * rsqrtf(rvar[bid] + BN_EPS);
        ws[WS_BIAS + bid] = beta[bid] - rmean[bid] * inv;
    }

    const float* fp = (c < 32) ? f0 : (c < 64) ? f1 : (c < 96) ? f2 : f3;
    const float4* base = (const float4*)(fp + ((size_t)b * 32 + (c & 31)) * S_TOT + half * 16384);
    float s = 0.f;
    #pragma unroll
    for (int j = 0; j < 16; ++j) {           // 256 thr * 16 * 4 = 16384 floats (half the channel)
        float4 v = base[j * 256 + t];
        s += (v.x + v.y) + (v.z + v.w);
    }
    red[t] = s;
    __syncthreads();
    #pragma unroll
    for (int off = 128; off > 0; off >>= 1) {
        if (t < off) red[t] += red[t + off];
        __syncthreads();
    }
    if (t == 0) ws[WS_PART + half * 256 + ch] = red[0];
}

// ---------------- K2: redundant route + stage + dual-expert GEMM + BN/ReLU/combine ----------------
__global__ __launch_bounds__(256, 2) void k_moe(
    const float* __restrict__ f0, const float* __restrict__ f1,
    const float* __restrict__ f2, const float* __restrict__ f3,
    const float* __restrict__ Wr, const float* __restrict__ br,
    const float* __restrict__ ws, float* __restrict__ out) {

    __shared__ uint4 tile4[2048];            // 32 KB swizzled xT tile
    __shared__ float pooled[256];
    __shared__ int   route_e[2];
    __shared__ float route_w[2];
    char* lds = (char*)tile4;

    int bid = blockIdx.x;                    // 512 = b(2) x st(256)
    int b = bid >> 8;
    int st = bid & 255;
    int s0 = st * S_TILE;
    int t = threadIdx.x;

    // ---- stage x tile -> LDS (float4 along s, bf16 b16-scatter into swizzled image) ----
    // layout: byte(s, c) = s*256 + ((c>>3) ^ (s&15))*16 + (c&7)*2   (same as r1/r3/r4)
    #pragma unroll
    for (int i = 0; i < 16; ++i) {
        int lin = i * 256 + t;               // 0..4095
        int c = lin >> 5;                    // 0..127
        int sq = lin & 31;                   // s-quad
        const float* fp = (c < 32) ? f0 : (c < 64) ? f1 : (c < 96) ? f2 : f3;
        float4 v = *(const float4*)(fp + ((size_t)b * 32 + (c & 31)) * S_TOT + s0 + sq * 4);
        int cpart = ((c >> 3) << 4) ^ 0;     // (c>>3)*16, xor applied per-s below
        int clow = (c & 7) * 2;
        int s = sq * 4;
        *(unsigned short*)(lds + (s + 0) * 256 + (cpart ^ (((s + 0) & 15) << 4)) + clow) = f2bf(v.x);
        *(unsigned short*)(lds + (s + 1) * 256 + (cpart ^ (((s + 1) & 15) << 4)) + clow) = f2bf(v.y);
        *(unsigned short*)(lds + (s + 2) * 256 + (cpart ^ (((s + 2) & 15) << 4)) + clow) = f2bf(v.z);
        *(unsigned short*)(lds + (s + 3) * 256 + (cpart ^ (((s + 3) & 15) << 4)) + clow) = f2bf(v.w);
    }

    // ---- redundant router (per block) ----
    pooled[t] = ws[WS_PART + t] + ws[WS_PART + 256 + t];
    __syncthreads();
    if (t < 64) {
        int l = t;
        const float s_inv = 1.0f / (float)S_TOT;
        float x0 = pooled[l] * s_inv;
        float x1 = pooled[64 + l] * s_inv;
        float y0 = pooled[128 + l] * s_inv;
        float y1 = pooled[192 + l] * s_inv;
        float lg[8];
        #pragma unroll
        for (int e = 0; e < 4; ++e) {
            float wc0 = Wr[e * MC_DIM + l];
            float wc1 = Wr[e * MC_DIM + 64 + l];
            lg[e] = x0 * wc0 + x1 * wc1;
            lg[4 + e] = y0 * wc0 + y1 * wc1;
        }
        #pragma unroll
        for (int msk = 32; msk >= 1; msk >>= 1) {
            #pragma unroll
            for (int e = 0; e < 8; ++e) lg[e] += __shfl_xor(lg[e], msk);
        }
        if (l == 0) {
            float probs[2][4];
            int top1[2];
            #pragma unroll
            for (int bb = 0; bb < 2; ++bb) {
                float lo[4];
                for (int e = 0; e < 4; ++e) lo[e] = lg[bb * 4 + e] + br[e];
                float mx = fmaxf(fmaxf(lo[0], lo[1]), fmaxf(lo[2], lo[3]));
                float sum = 0.f;
                for (int e = 0; e < 4; ++e) { probs[bb][e] = expf(lo[e] - mx); sum += probs[bb][e]; }
                for (int e = 0; e < 4; ++e) probs[bb][e] /= sum;
                int e0 = 0; float v0 = probs[bb][0];
                for (int e = 1; e < 4; ++e) if (probs[bb][e] > v0) { v0 = probs[bb][e]; e0 = e; }
                int e1 = -1; float v1 = -1.f;
                for (int e = 0; e < 4; ++e) if (e != e0 && probs[bb][e] > v1) { v1 = probs[bb][e]; e1 = e; }
                top1[bb] = e0;
                if (bb == b) {
                    float inv = 1.f / (v0 + v1);
                    route_e[0] = e0; route_e[1] = e1;
                    route_w[0] = v0 * inv; route_w[1] = v1 * inv;
                }
            }
            if (bid == 0) {
                float aux = 0.f;
                for (int e = 0; e < 4; ++e) {
                    float fe = 0.5f * ((top1[0] == e) + (top1[1] == e));
                    float pe = 0.5f * (probs[0][e] + probs[1][e]);
                    aux += fe * pe;
                }
                out[(size_t)8388608] = 4.f * aux;
            }
        }
    }
    __syncthreads();                          // staging LDS + route both ready

    int e0 = route_e[0], e1 = route_e[1];
    float w0 = route_w[0], w1 = route_w[1];
    const unsigned short* W2 = (const unsigned short*)(ws + WS_W2);
    const float* bias2 = ws + WS_BIAS;

    int wv = t >> 6, l = t & 63;
    int o0 = wv * 32;
    int lr = l & 15, lg2 = l >> 4;

    f32x4 acc[2][2][8];
    #pragma unroll
    for (int ee = 0; ee < 2; ++ee)
        #pragma unroll
        for (int of = 0; of < 2; ++of)
            #pragma unroll
            for (int sf = 0; sf < 8; ++sf)
                acc[ee][of][sf] = (f32x4){0.f, 0.f, 0.f, 0.f};

    #pragma unroll
    for (int kk = 0; kk < 4; ++kk) {
        short8 a[2][2];
        #pragma unroll
        for (int ee = 0; ee < 2; ++ee) {
            int e = ee ? e1 : e0;
            #pragma unroll
            for (int of = 0; of < 2; ++of) {
                int o = o0 + of * 16 + lr;   // A: row = lane&15
                a[ee][of] = *(const short8*)(W2 + ((size_t)(e * O_DIM + o) * MC_DIM + kk * 32 + lg2 * 8));
            }
        }
        #pragma unroll
        for (int sf = 0; sf < 8; ++sf) {
            int sl = sf * 16 + lr;           // B: col = lane&15
            int gr = kk * 4 + lg2;
            int byte = sl * 256 + ((gr ^ lr) << 4);
            short8 bb = *(const short8*)(lds + byte);
            #pragma unroll
            for (int ee = 0; ee < 2; ++ee)
                #pragma unroll
                for (int of = 0; of < 2; ++of)
                    acc[ee][of][sf] = __builtin_amdgcn_mfma_f32_16x16x32_bf16(
                        a[ee][of], bb, acc[ee][of][sf], 0, 0, 0);
        }
    }

    #pragma unroll
    for (int of = 0; of < 2; ++of) {
        #pragma unroll
        for (int r = 0; r < 4; ++r) {
            int o = o0 + of * 16 + lg2 * 4 + r;   // C/D: row = (lane>>4)*4 + reg
            float bA = bias2[e0 * O_DIM + o];
            float bB = bias2[e1 * O_DIM + o];
            float* orow = out + ((size_t)(b * O_DIM + o)) * S_TOT + s0;
            #pragma unroll
            for (int sf = 0; sf < 8; ++sf) {
                float y0 = fmaxf(acc[0][of][sf][r] + bA, 0.f);
                float y1 = fmaxf(acc[1][of][sf][r] + bB, 0.f);
                orow[sf * 16 + lr] = w0 * y0 + w1 * y1;
            }
        }
    }
}

extern "C" void kernel_launch(void* const* d_in, const int* in_sizes, int n_in,
                              void* d_out, int out_size, void* d_ws, size_t ws_size,
                              hipStream_t stream) {
    const float* f0    = (const float*)d_in[0];
    const float* f1    = (const float*)d_in[1];
    const float* f2    = (const float*)d_in[2];
    const float* f3    = (const float*)d_in[3];
    const float* Wc    = (const float*)d_in[4];
    const float* gamma = (const float*)d_in[5];
    const float* beta  = (const float*)d_in[6];
    const float* rmean = (const float*)d_in[7];
    const float* rvar  = (const float*)d_in[8];
    const float* Wr    = (const float*)d_in[9];
    const float* br    = (const float*)d_in[10];
    float* ws  = (float*)d_ws;
    float* out = (float*)d_out;

    hipLaunchKernelGGL(k_pool, dim3(512), dim3(256), 0, stream,
                       f0, f1, f2, f3, Wc, gamma, beta, rmean, rvar, ws);
    hipLaunchKernelGGL(k_moe, dim3(512), dim3(256), 0, stream,
                       f0, f1, f2, f3, Wr, br, ws, out);
}